// Round 6
// baseline (453.369 us; speedup 1.0000x reference)
//
#include <hip/hip_runtime.h>
#include <stdint.h>
#include <stddef.h>

#define NB 4
#define NC 256
#define NSP 4096
#define NG 32
#define CPG 8
#define GEPS 1e-5f
#define SCALE 0.0625f  // d^-0.5, d=256

typedef __attribute__((ext_vector_type(8))) short s8v;
typedef __attribute__((ext_vector_type(4))) float f4v;
typedef __attribute__((ext_vector_type(4))) unsigned short us4v;

__device__ __forceinline__ float b2f(unsigned short h) {
  union { unsigned u; float f; } x; x.u = ((unsigned)h) << 16; return x.f;
}
__device__ __forceinline__ unsigned short f2b(float f) {
  union { float f; unsigned u; } x; x.f = f;
  unsigned r = x.u + 0x7fffu + ((x.u >> 16) & 1u);
  return (unsigned short)(r >> 16);
}

// -------------------- fp32 -> bf16 convert (weights) --------------------
__global__ __launch_bounds__(256) void cvt_kernel(const float* __restrict__ in,
                                                  unsigned short* __restrict__ out, int n) {
  int i = (blockIdx.x * 256 + threadIdx.x) * 4;
  if (i < n) {
    float4 v = *(const float4*)(in + i);
    us4v p;
    p[0] = f2b(v.x); p[1] = f2b(v.y); p[2] = f2b(v.z); p[3] = f2b(v.w);
    *(us4v*)(out + i) = p;
  }
}

// -------------------- GroupNorm: x fp32 (B,C,N) -> xn bf16 (B,N,C) --------------------
__global__ __launch_bounds__(256) void gn_kernel(
    const float* __restrict__ x, const float* __restrict__ w,
    const float* __restrict__ bias, unsigned short* __restrict__ xn) {
  int b = blockIdx.x >> 5;
  int g = blockIdx.x & 31;
  const float* xp = x + ((size_t)b * NC + (size_t)g * CPG) * NSP;
  int t = threadIdx.x;
  float s = 0.f, ss = 0.f;
  for (int i = 4 * t; i < CPG * NSP; i += 1024) {
    float4 v = *(const float4*)(xp + i);
    s += v.x + v.y + v.z + v.w;
    ss += v.x * v.x + v.y * v.y + v.z * v.z + v.w * v.w;
  }
  __shared__ float r1[256], r2[256];
  r1[t] = s; r2[t] = ss;
  __syncthreads();
  for (int off = 128; off > 0; off >>= 1) {
    if (t < off) { r1[t] += r1[t + off]; r2[t] += r2[t + off]; }
    __syncthreads();
  }
  float mean = r1[0] * (1.f / (CPG * NSP));
  float var  = r2[0] * (1.f / (CPG * NSP)) - mean * mean;
  float rstd = rsqrtf(var + GEPS);
  float wv[CPG], bv[CPG];
  for (int c = 0; c < CPG; c++) {
    wv[c] = w[g * CPG + c] * rstd;
    bv[c] = bias[g * CPG + c] - mean * wv[c];
  }
  for (int n = t; n < NSP; n += 256) {
    s8v pk;
    for (int c = 0; c < CPG; c++) {
      float v = xp[(size_t)c * NSP + n];
      ((unsigned short*)&pk)[c] = f2b(v * wv[c] + bv[c]);
    }
    *(s8v*)(xn + ((size_t)(b * NSP + n) * NC + g * CPG)) = pk;
  }
}

// ------ Generic NT GEMM: C[m][n] = scale*sum_k A[m][k]*Bt[n][k] (+bias[m]) (+res) ------
// A: (M,K) bf16 k-contig. Bt: (N,K) bf16 k-contig. bias/res fp32.
// F32OUT: C fp32 normal store. else bf16 (STORE_T: transposed (N,M)).
template<int STORE_T, int HAS_BIAS, int HAS_RES, int F32OUT>
__global__ __launch_bounds__(256) void gemm_nt(
    const unsigned short* __restrict__ A, const unsigned short* __restrict__ Bt,
    void* __restrict__ Cv, const float* __restrict__ bias,
    const float* __restrict__ res,
    int M, int N, int K, int ldC, float scale,
    long long sA, long long sB, long long sC, long long sR) {
  A  += (size_t)blockIdx.z * sA;
  Bt += (size_t)blockIdx.z * sB;
  if (HAS_RES) res += (size_t)blockIdx.z * sR;
  const int m0 = blockIdx.y * 128, n0 = blockIdx.x * 128;
  __shared__ unsigned short As[128 * 32], Bs[128 * 32];
  const int t = threadIdx.x;
  const int lane = t & 63, wave = t >> 6;
  const int wm = (wave >> 1) * 64, wn = (wave & 1) * 64;
  const int l16 = lane & 15, quad = lane >> 4;
  const int srow = t >> 2, skc = (t & 3) * 8;

  f4v acc[4][4];
  for (int mi = 0; mi < 4; mi++)
    for (int ni = 0; ni < 4; ni++)
      acc[mi][ni] = (f4v){0.f, 0.f, 0.f, 0.f};

  const unsigned short* Ag0 = A  + (size_t)(m0 + srow) * K + skc;
  const unsigned short* Ag1 = A  + (size_t)(m0 + srow + 64) * K + skc;
  const unsigned short* Bg0 = Bt + (size_t)(n0 + srow) * K + skc;
  const unsigned short* Bg1 = Bt + (size_t)(n0 + srow + 64) * K + skc;

  for (int k0 = 0; k0 < K; k0 += 32) {
    s8v a0 = *(const s8v*)(Ag0 + k0);
    s8v a1 = *(const s8v*)(Ag1 + k0);
    s8v b0 = *(const s8v*)(Bg0 + k0);
    s8v b1 = *(const s8v*)(Bg1 + k0);
    __syncthreads();
    *(s8v*)(As + srow * 32 + skc) = a0;
    *(s8v*)(As + (srow + 64) * 32 + skc) = a1;
    *(s8v*)(Bs + srow * 32 + skc) = b0;
    *(s8v*)(Bs + (srow + 64) * 32 + skc) = b1;
    __syncthreads();
    s8v af[4], bfr[4];
    for (int mi = 0; mi < 4; mi++)
      af[mi] = *(const s8v*)(As + (wm + mi * 16 + l16) * 32 + quad * 8);
    for (int ni = 0; ni < 4; ni++)
      bfr[ni] = *(const s8v*)(Bs + (wn + ni * 16 + l16) * 32 + quad * 8);
    for (int mi = 0; mi < 4; mi++)
      for (int ni = 0; ni < 4; ni++)
        acc[mi][ni] = __builtin_amdgcn_mfma_f32_16x16x32_bf16(af[mi], bfr[ni], acc[mi][ni], 0, 0, 0);
  }

  for (int mi = 0; mi < 4; mi++) {
    const int rb = m0 + wm + mi * 16 + quad * 4;
    for (int ni = 0; ni < 4; ni++) {
      const int col = n0 + wn + ni * 16 + l16;
      f4v a = acc[mi][ni];
      if (F32OUT) {
        float* C = (float*)Cv + (size_t)blockIdx.z * sC;
        for (int r = 0; r < 4; r++) {
          float v = a[r] * scale;
          if (HAS_BIAS) v += bias[rb + r];
          if (HAS_RES) v += res[(size_t)(rb + r) * ldC + col];
          C[(size_t)(rb + r) * ldC + col] = v;
        }
      } else {
        unsigned short* C = (unsigned short*)Cv + (size_t)blockIdx.z * sC;
        if (STORE_T) {
          us4v pk;
          for (int r = 0; r < 4; r++) {
            float v = a[r] * scale;
            if (HAS_BIAS) v += bias[rb + r];
            pk[r] = (unsigned short)f2b(v);
          }
          *(us4v*)(C + (size_t)col * ldC + rb) = pk;
        } else {
          for (int r = 0; r < 4; r++) {
            float v = a[r] * scale;
            if (HAS_BIAS) v += bias[rb + r];
            if (HAS_RES) v += res[(size_t)(rb + r) * ldC + col];
            C[(size_t)(rb + r) * ldC + col] = f2b(v);
          }
        }
      }
    }
  }
}

// -------------------- Flash attention: q,k (B,N,d) d-contig; v (B,d,N) j-contig --------
// grid (NSP/64, NB), 256 threads. Wave w owns Q-rows [qt*64+w*16, +16).
__global__ __launch_bounds__(256) void flash_kernel(
    const unsigned short* __restrict__ q, const unsigned short* __restrict__ k,
    const unsigned short* __restrict__ v, unsigned short* __restrict__ o) {
  const int b = blockIdx.y, qt = blockIdx.x;
  const size_t sNC = (size_t)NSP * NC;
  const unsigned short* qb = q + b * sNC;
  const unsigned short* kb = k + b * sNC;
  const unsigned short* vb = v + b * sNC;
  unsigned short* ob = o + b * sNC;
  const int t = threadIdx.x, lane = t & 63, w = t >> 6;
  const int l16 = lane & 15, quad = lane >> 4;

  __shared__ unsigned short Ks[32 * 264];
  __shared__ unsigned short Vs[256 * 40];
  __shared__ unsigned short Ps[4 * 16 * 40];

  const int ibase = qt * 64 + w * 16;
  s8v qf[8];
  for (int kc = 0; kc < 8; kc++)
    qf[kc] = *(const s8v*)(qb + (size_t)(ibase + l16) * NC + kc * 32 + quad * 8);

  f4v accO[16];
  for (int dt = 0; dt < 16; dt++) accO[dt] = (f4v){0.f, 0.f, 0.f, 0.f};
  float m_r[4], l_r[4];
  for (int r = 0; r < 4; r++) { m_r[r] = -1e30f; l_r[r] = 0.f; }

  const int krow = t >> 3, kseg = (t & 7) * 32;
  unsigned short* Pw = Ps + w * (16 * 40);

  for (int jt = 0; jt < NSP / 32; jt++) {
    __syncthreads();
    const unsigned short* kg = kb + (size_t)(jt * 32 + krow) * NC + kseg;
    for (int c = 0; c < 4; c++)
      *(s8v*)(Ks + krow * 264 + kseg + c * 8) = *(const s8v*)(kg + c * 8);
    const unsigned short* vg = vb + (size_t)t * NSP + jt * 32;
    for (int c = 0; c < 4; c++)
      *(s8v*)(Vs + t * 40 + c * 8) = *(const s8v*)(vg + c * 8);
    __syncthreads();

    f4v accS[2];
    accS[0] = (f4v){0.f, 0.f, 0.f, 0.f};
    accS[1] = (f4v){0.f, 0.f, 0.f, 0.f};
    for (int kc = 0; kc < 8; kc++) {
      s8v kf0 = *(const s8v*)(Ks + (l16)      * 264 + kc * 32 + quad * 8);
      s8v kf1 = *(const s8v*)(Ks + (16 + l16) * 264 + kc * 32 + quad * 8);
      accS[0] = __builtin_amdgcn_mfma_f32_16x16x32_bf16(qf[kc], kf0, accS[0], 0, 0, 0);
      accS[1] = __builtin_amdgcn_mfma_f32_16x16x32_bf16(qf[kc], kf1, accS[1], 0, 0, 0);
    }

    float al_r[4];
    for (int r = 0; r < 4; r++) {
      float mv = fmaxf(accS[0][r], accS[1][r]) * SCALE;
      for (int msk = 1; msk < 16; msk <<= 1) mv = fmaxf(mv, __shfl_xor(mv, msk, 64));
      float mt = fmaxf(m_r[r], mv);
      float al = __expf(m_r[r] - mt);
      float p0 = __expf(accS[0][r] * SCALE - mt);
      float p1 = __expf(accS[1][r] * SCALE - mt);
      accS[0][r] = p0; accS[1][r] = p1;
      float s = p0 + p1;
      for (int msk = 1; msk < 16; msk <<= 1) s += __shfl_xor(s, msk, 64);
      l_r[r] = l_r[r] * al + s;
      m_r[r] = mt;
      al_r[r] = al;
    }
    for (int dt = 0; dt < 16; dt++)
      for (int r = 0; r < 4; r++) accO[dt][r] *= al_r[r];

    for (int n = 0; n < 2; n++)
      for (int r = 0; r < 4; r++)
        Pw[(quad * 4 + r) * 40 + n * 16 + l16] = f2b(accS[n][r]);
    s8v pf = *(const s8v*)(Pw + l16 * 40 + quad * 8);

    for (int dt = 0; dt < 16; dt++) {
      s8v vf = *(const s8v*)(Vs + (dt * 16 + l16) * 40 + quad * 8);
      accO[dt] = __builtin_amdgcn_mfma_f32_16x16x32_bf16(pf, vf, accO[dt], 0, 0, 0);
    }
  }

  float inv[4];
  for (int r = 0; r < 4; r++) inv[r] = 1.f / l_r[r];
  for (int dt = 0; dt < 16; dt++)
    for (int r = 0; r < 4; r++)
      ob[(size_t)(ibase + quad * 4 + r) * NC + dt * 16 + l16] = f2b(accO[dt][r] * inv[r]);
}

extern "C" void kernel_launch(void* const* d_in, const int* in_sizes, int n_in,
                              void* d_out, int out_size, void* d_ws, size_t ws_size,
                              hipStream_t stream) {
  const float* x      = (const float*)d_in[0];
  const float* norm_w = (const float*)d_in[1];
  const float* norm_b = (const float*)d_in[2];
  const float* qkv_w  = (const float*)d_in[3];
  const float* qkv_b  = (const float*)d_in[4];
  const float* proj_w = (const float*)d_in[5];
  const float* proj_b = (const float*)d_in[6];
  float* out = (float*)d_out;  // OUTPUT IS FP32 (reference returns float32)

  char* ws = (char*)d_ws;
  unsigned short* wq = (unsigned short*)ws;                     // 384 KB
  unsigned short* wp = (unsigned short*)(ws + 3 * NC * NC * 2); // 128 KB
  char* wst = ws + (1 << 20);
  const size_t szBNC = (size_t)NB * NSP * NC * 2;  // 8.4 MB (bf16)
  unsigned short* xn = (unsigned short*)wst;              // reused as `at` later
  unsigned short* q  = (unsigned short*)(wst + szBNC);
  unsigned short* k  = (unsigned short*)(wst + 2 * szBNC);
  unsigned short* v  = (unsigned short*)(wst + 3 * szBNC);
  unsigned short* at = xn;   // xn dead after QKV GEMMs

  cvt_kernel<<<dim3(3 * NC * NC / 1024), 256, 0, stream>>>(qkv_w, wq, 3 * NC * NC);
  cvt_kernel<<<dim3(NC * NC / 1024), 256, 0, stream>>>(proj_w, wp, NC * NC);
  gn_kernel<<<dim3(NB * NG), 256, 0, stream>>>(x, norm_w, norm_b, xn);

  const long long sNC = (long long)NSP * NC;
  // q,k stored transposed -> (B,N,d); v normal -> (B,d,N)
  gemm_nt<1, 1, 0, 0><<<dim3(NSP / 128, NC / 128, NB), 256, 0, stream>>>(
      wq, xn, q, qkv_b, nullptr, NC, NSP, NC, NC, 1.f, 0, sNC, sNC, 0);
  gemm_nt<1, 1, 0, 0><<<dim3(NSP / 128, NC / 128, NB), 256, 0, stream>>>(
      wq + NC * NC, xn, k, qkv_b + NC, nullptr, NC, NSP, NC, NC, 1.f, 0, sNC, sNC, 0);
  gemm_nt<0, 1, 0, 0><<<dim3(NSP / 128, NC / 128, NB), 256, 0, stream>>>(
      wq + 2 * NC * NC, xn, v, qkv_b + 2 * NC, nullptr, NC, NSP, NC, NSP, 1.f, 0, sNC, sNC, 0);

  // flash attention: q,k,v -> at (B,N,C) bf16
  flash_kernel<<<dim3(NSP / 64, NB), 256, 0, stream>>>(q, k, v, at);

  // proj + bias + residual(x fp32) -> out FP32 (B,C,N)
  gemm_nt<0, 1, 1, 1><<<dim3(NSP / 128, NC / 128, NB), 256, 0, stream>>>(
      wp, at, out, proj_b, x, NC, NSP, NC, NSP, 1.f, 0, sNC, sNC, sNC);
}